// Round 4
// baseline (421.666 us; speedup 1.0000x reference)
//
#include <hip/hip_runtime.h>
#include <math.h>

namespace {
constexpr int B_   = 8;
constexpr int DIM_ = 2048;
constexpr int H_   = 16;
constexpr int QLR_ = 1536;
constexpr int KVLR_= 512;
constexpr int DN_  = 128;
constexpr int DR_  = 64;
constexpr int DV_  = 128;
constexpr int TPRE_= 8191;
constexpr int CE_  = 576;    // KVLR + DR
constexpr int NCH_ = 32;     // chunks over T=8192
constexpr int CT_  = 256;    // t per chunk
constexpr int TS_  = 32;     // rows per LDS subtile (double-buffered)
constexpr int PSTR_= 20;     // p_lds row stride
constexpr float EPS_ = 1e-6f;
constexpr float SCALE_ = 0.07216878364870322f; // (DN+DR)^-0.5

// workspace layout (float offsets)
constexpr size_t WS_QLAT  = 0;
constexpr size_t WS_KVPE  = WS_QLAT  + (size_t)B_*QLR_;
constexpr size_t WS_KVNEW = WS_KVPE  + (size_t)B_*CE_;
constexpr size_t WS_PENEW = WS_KVNEW + (size_t)B_*KVLR_;
constexpr size_t WS_QRS   = WS_PENEW + (size_t)B_*DR_;
constexpr size_t WS_QNOPE = WS_QRS   + (size_t)B_;
constexpr size_t WS_QT    = WS_QNOPE + (size_t)B_*H_*DN_;   // qTT: [b][h][576]
constexpr size_t WS_MLOC  = WS_QT    + (size_t)B_*CE_*H_;
constexpr size_t WS_LLOC  = WS_MLOC  + (size_t)B_*H_*NCH_;
constexpr size_t WS_OUT2  = WS_LLOC  + (size_t)B_*H_*NCH_;
constexpr size_t WS_OPART = WS_OUT2  + (size_t)B_*DIM_;     // [b][h][chunk][512]
} // namespace

__device__ __forceinline__ void gload16(const float* src, float* ldsDst) {
  __builtin_amdgcn_global_load_lds((const __attribute__((address_space(1))) void*)src,
                                   (__attribute__((address_space(3))) void*)ldsDst,
                                   16, 0, 0);
}

// sum across each 16-lane group via DPP (VALU pipe, keeps DS unit free)
__device__ __forceinline__ float rsum16(float v) {
  int x = __float_as_int(v);
  v += __int_as_float(__builtin_amdgcn_update_dpp(0, x, 0xB1, 0xF, 0xF, true));  // quad_perm xor1
  x = __float_as_int(v);
  v += __int_as_float(__builtin_amdgcn_update_dpp(0, x, 0x4E, 0xF, 0xF, true));  // quad_perm xor2
  x = __float_as_int(v);
  v += __int_as_float(__builtin_amdgcn_update_dpp(0, x, 0x141, 0xF, 0xF, true)); // row_half_mirror
  x = __float_as_int(v);
  v += __int_as_float(__builtin_amdgcn_update_dpp(0, x, 0x140, 0xF, 0xF, true)); // row_mirror
  return v;
}

// ---------------- K1: q_latent = x@wq_a^T + b ; kvpe = x@wkv_a^T + b ----------------
__global__ __launch_bounds__(256) void mla_k1(const float* __restrict__ x,
                                              const float* __restrict__ wqa,
                                              const float* __restrict__ bqa,
                                              const float* __restrict__ wkva,
                                              const float* __restrict__ bkva,
                                              float* __restrict__ ws) {
  const int w = threadIdx.x >> 6, l = threadIdx.x & 63;
  const int r = blockIdx.x * 4 + w;  // 0..2111
  const float* W; const float* bias; float* out; int rr; int ostride;
  if (r < QLR_) { W = wqa;  bias = bqa;  out = ws + WS_QLAT; rr = r;        ostride = QLR_; }
  else          { W = wkva; bias = bkva; out = ws + WS_KVPE; rr = r - QLR_; ostride = CE_;  }
  const float4* wp = (const float4*)(W + (size_t)rr * DIM_);
  const float4* x4 = (const float4*)x;
  float4 wv[8];
#pragma unroll
  for (int j = 0; j < 8; ++j) wv[j] = wp[l + 64 * j];
  float acc[B_];
#pragma unroll
  for (int b = 0; b < B_; ++b) acc[b] = 0.f;
#pragma unroll
  for (int b = 0; b < B_; ++b) {
#pragma unroll
    for (int j = 0; j < 8; ++j) {
      const float4 xv = x4[b * (DIM_ / 4) + l + 64 * j];
      acc[b] = fmaf(wv[j].x, xv.x, fmaf(wv[j].y, xv.y, fmaf(wv[j].z, xv.z, fmaf(wv[j].w, xv.w, acc[b]))));
    }
  }
#pragma unroll
  for (int b = 0; b < B_; ++b)
#pragma unroll
    for (int s = 32; s; s >>= 1) acc[b] += __shfl_xor(acc[b], s);
  if (l == 0) {
    const float b0 = bias[rr];
#pragma unroll
    for (int b = 0; b < B_; ++b) out[b * ostride + rr] = acc[b] + b0;
  }
}

// ---------------- K2: kv rms-norm + k_pe rope + q rms scales ----------------
__global__ __launch_bounds__(256) void mla_k2(const float* __restrict__ kvnw,
                                              const float* __restrict__ fcos,
                                              const float* __restrict__ fsin,
                                              float* __restrict__ ws) {
  const int tid = threadIdx.x;
  const int b = tid >> 5, i = tid & 31;
  const float* kvpe = ws + WS_KVPE + b * CE_;
  float ss = 0.f;
#pragma unroll
  for (int j = 0; j < KVLR_ / 32; ++j) { const float v = kvpe[i + 32 * j]; ss = fmaf(v, v, ss); }
#pragma unroll
  for (int s = 16; s; s >>= 1) ss += __shfl_xor(ss, s, 32);
  const float scale = 1.0f / sqrtf(ss / (float)KVLR_ + EPS_);
  float* kvn = ws + WS_KVNEW + b * KVLR_;
#pragma unroll
  for (int j = 0; j < KVLR_ / 32; ++j) {
    const int c = i + 32 * j;
    kvn[c] = kvpe[c] * kvnw[c] * scale;
  }
  { // rope new k_pe
    const float xr = kvpe[KVLR_ + 2 * i], xi = kvpe[KVLR_ + 2 * i + 1];
    const float c = fcos[i], s = fsin[i];
    float* pen = ws + WS_PENEW + b * DR_;
    pen[2 * i]     = xr * c - xi * s;
    pen[2 * i + 1] = xr * s + xi * c;
  }
  { // q latent rms scale per batch
    const float* p = ws + WS_QLAT + b * QLR_;
    float sq = 0.f;
#pragma unroll
    for (int j = 0; j < QLR_ / 32; ++j) { const float v = p[i + 32 * j]; sq = fmaf(v, v, sq); }
#pragma unroll
    for (int s = 16; s; s >>= 1) sq += __shfl_xor(sq, s, 32);
    if (i == 0) ws[WS_QRS + b] = 1.0f / sqrtf(sq / (float)QLR_ + EPS_);
  }
}

// ---------------- K3: q = rms(q_lat)*g @ wq_b^T + b ; split nope / rope(pe) ----------------
__global__ __launch_bounds__(256) void mla_k3(const float* __restrict__ qnw,
                                              const float* __restrict__ wqb,
                                              const float* __restrict__ bqb,
                                              const float* __restrict__ fcos,
                                              const float* __restrict__ fsin,
                                              float* __restrict__ ws) {
  const int w = threadIdx.x >> 6, l = threadIdx.x & 63;
  const int r0 = blockIdx.x * 8 + w * 2;  // 0..3070
  const float4* w0p = (const float4*)(wqb + (size_t)r0 * QLR_);
  const float4* w1p = (const float4*)(wqb + (size_t)(r0 + 1) * QLR_);
  const float4* g4  = (const float4*)qnw;
  const float4* x4  = (const float4*)(ws + WS_QLAT);
  float4 wg0[6], wg1[6];
#pragma unroll
  for (int j = 0; j < 6; ++j) {
    const int c4 = l + 64 * j;
    const float4 a = w0p[c4], bb = w1p[c4], g = g4[c4];
    wg0[j].x = a.x * g.x; wg0[j].y = a.y * g.y; wg0[j].z = a.z * g.z; wg0[j].w = a.w * g.w;
    wg1[j].x = bb.x * g.x; wg1[j].y = bb.y * g.y; wg1[j].z = bb.z * g.z; wg1[j].w = bb.w * g.w;
  }
  float acc0[B_], acc1[B_];
#pragma unroll
  for (int b = 0; b < B_; ++b) { acc0[b] = 0.f; acc1[b] = 0.f; }
#pragma unroll
  for (int b = 0; b < B_; ++b) {
#pragma unroll
    for (int j = 0; j < 6; ++j) {
      const float4 xv = x4[b * (QLR_ / 4) + l + 64 * j];
      acc0[b] = fmaf(wg0[j].x, xv.x, fmaf(wg0[j].y, xv.y, fmaf(wg0[j].z, xv.z, fmaf(wg0[j].w, xv.w, acc0[b]))));
      acc1[b] = fmaf(wg1[j].x, xv.x, fmaf(wg1[j].y, xv.y, fmaf(wg1[j].z, xv.z, fmaf(wg1[j].w, xv.w, acc1[b]))));
    }
  }
#pragma unroll
  for (int b = 0; b < B_; ++b)
#pragma unroll
    for (int s = 32; s; s >>= 1) {
      acc0[b] += __shfl_xor(acc0[b], s);
      acc1[b] += __shfl_xor(acc1[b], s);
    }
  if (l == 0) {
    const int h = r0 / (DN_ + DR_);
    const int j0 = r0 - h * (DN_ + DR_);
    const float b0 = bqb[r0], b1 = bqb[r0 + 1];
    if (j0 < DN_) {
      float* qn = ws + WS_QNOPE;
#pragma unroll
      for (int b = 0; b < B_; ++b) {
        const float sb = ws[WS_QRS + b];
        qn[(b * H_ + h) * DN_ + j0]     = acc0[b] * sb + b0;
        qn[(b * H_ + h) * DN_ + j0 + 1] = acc1[b] * sb + b1;
      }
    } else {
      const int i = (j0 - DN_) >> 1;
      const float c = fcos[i], s = fsin[i];
      float* qTT = ws + WS_QT;
#pragma unroll
      for (int b = 0; b < B_; ++b) {
        const float sb = ws[WS_QRS + b];
        const float xr = acc0[b] * sb + b0, xi = acc1[b] * sb + b1;
        qTT[((size_t)(b * H_ + h)) * CE_ + KVLR_ + 2 * i]     = xr * c - xi * s;
        qTT[((size_t)(b * H_ + h)) * CE_ + KVLR_ + 2 * i + 1] = xr * s + xi * c;
      }
    }
  }
}

// ---------------- K4: q_abs[b][h][c] = sum_d q_nope[b][h][d] * wkv_b[h][d][c] ----------------
__global__ __launch_bounds__(256) void mla_k4(const float* __restrict__ wkvb,
                                              float* __restrict__ ws) {
  __shared__ float red[7 * 32 * B_];
  const int h = blockIdx.y;
  const int strip = blockIdx.x;
  const int tid = threadIdx.x;
  const int c = tid & 31, dg = tid >> 5;
  const int cg = strip * 32 + c;
  const float* qn = ws + WS_QNOPE;
  float acc[B_];
#pragma unroll
  for (int b = 0; b < B_; ++b) acc[b] = 0.f;
  const float* wp = wkvb + (size_t)h * 256 * KVLR_ + cg;
#pragma unroll
  for (int dd = 0; dd < 16; ++dd) {
    const int d = dg * 16 + dd;
    const float wv = wp[(size_t)d * KVLR_];
#pragma unroll
    for (int b = 0; b < B_; ++b) acc[b] = fmaf(qn[(b * H_ + h) * DN_ + d], wv, acc[b]);
  }
  if (dg > 0) {
#pragma unroll
    for (int b = 0; b < B_; ++b) red[(((dg - 1) * 32) + c) * B_ + b] = acc[b];
  }
  __syncthreads();
  if (dg == 0) {
    float* qTT = ws + WS_QT;
#pragma unroll
    for (int b = 0; b < B_; ++b) {
      float v = acc[b];
#pragma unroll
      for (int g = 0; g < 7; ++g) v += red[(g * 32 + c) * B_ + b];
      qTT[((size_t)(b * H_ + h)) * CE_ + cg] = v;
    }
  }
}

// ---------------- K5: fused flash-decode, q-in-registers, all-wave score ----------------
// 512 thr, grid (32, 8), 1 block/CU. TS=32 double-buffered kv staged via
// global_load_lds (linear [32][576] rows, stride 576 == 0 mod 32 -> conflict-free).
// Score: thread = (t8-group [wave], h-pair, c-split16); q[2][36] persistent in
// VGPRs (loaded once from qTT) -> zero q LDS reads; 8 kv b128 per 64 FMA; DPP
// reduce over the 16 c-split lanes (VALU pipe). PV: thread = (c-quad, h-quad),
// o[4][4] persistent; 2 b128 per 16 FMA. All 8 waves active in every phase.
__global__ __launch_bounds__(512, 2) void mla_k5(const float* __restrict__ kvpre,
                                                 const float* __restrict__ pepre,
                                                 float* __restrict__ ws) {
  __shared__ float kv_lds[2][TS_ * CE_];  // 2 x 32 x 576 x 4B = 147.5 KB
  __shared__ float p_lds[TS_ * PSTR_];    // 2.5 KB
  __shared__ float m_st[H_], l_st[H_], f_st[H_];

  const int b = blockIdx.y, chunk = blockIdx.x;
  const int t0 = chunk * CT_;
  const int tid = threadIdx.x;
  const int w = tid >> 6, l = tid & 63;
  // score roles
  const int cs = l & 15;             // c-split: 36 floats each
  const int hl = l >> 4;             // 0..3
  const int tg = w >> 1;             // t-group: rows tg*8 .. tg*8+7
  const int hg = (w & 1) * 4 + hl;   // 0..7 -> heads 2hg, 2hg+1
  // PV roles
  const int c4p = tid >> 2, h4p = tid & 3;

  const float* kvnew = ws + WS_KVNEW + b * KVLR_;
  const float* penew = ws + WS_PENEW + b * DR_;

  auto stageKV = [&](float* buf, int s) {
    const int ts0 = t0 + s * TS_;
#pragma unroll
    for (int k = 0; k < 9; ++k) {          // 32*576/4 = 4608 f4 / 512 thr = 9
      const int i = w + 8 * k;             // wave-strided instr index
      const int f = i * 64 + l;            // f4 index in subtile
      const int tl = f / 144;
      const int c4 = f - tl * 144;
      const int tgl = ts0 + tl;
      const float* src;
      if (tgl < TPRE_) {
        src = (c4 < 128) ? (kvpre + ((size_t)b * TPRE_ + tgl) * KVLR_ + 4 * c4)
                         : (pepre + ((size_t)b * TPRE_ + tgl) * DR_ + 4 * (c4 - 128));
      } else {
        src = (c4 < 128) ? (kvnew + 4 * c4) : (penew + 4 * (c4 - 128));
      }
      gload16(src, buf + (size_t)i * 64 * 4);
    }
  };

  stageKV(kv_lds[0], 0);   // start HBM early

  // --- persistent q registers: heads 2hg, 2hg+1, c-range [cs*36, cs*36+36) ---
  float4 q0v[9], q1v[9];
  {
    const float* qb0 = ws + WS_QT + ((size_t)(b * H_) + 2 * hg) * CE_ + cs * 36;
    const float* qb1 = qb0 + CE_;
#pragma unroll
    for (int j = 0; j < 9; ++j) {
      q0v[j] = *(const float4*)(qb0 + 4 * j);
      q1v[j] = *(const float4*)(qb1 + 4 * j);
    }
  }
  if (tid < H_) { m_st[tid] = -3.4e38f; l_st[tid] = 0.f; }

  float o[4][4];
#pragma unroll
  for (int cc = 0; cc < 4; ++cc)
#pragma unroll
    for (int hh = 0; hh < 4; ++hh) o[cc][hh] = 0.f;

  for (int s = 0; s < CT_ / TS_; ++s) {   // 8 subtiles of 32 rows
    __syncthreads();                       // buf[s&1] staged; prev PV reads done
    if (s + 1 < CT_ / TS_) stageKV(kv_lds[(s + 1) & 1], s + 1);  // prefetch
    const float* bufc = kv_lds[s & 1];

    // --- scores: 8 t-rows x 2 h x 36 c per thread, q from regs ---
    {
      float acc[8][2];
#pragma unroll
      for (int tt = 0; tt < 8; ++tt) { acc[tt][0] = 0.f; acc[tt][1] = 0.f; }
      const float* kb = bufc + (tg * 8) * CE_ + cs * 36;
#pragma unroll
      for (int j = 0; j < 9; ++j) {
        float4 kv[8];
#pragma unroll
        for (int tt = 0; tt < 8; ++tt) kv[tt] = *(const float4*)(kb + tt * CE_ + 4 * j);
#pragma unroll
        for (int tt = 0; tt < 8; ++tt) {
          const float4 k = kv[tt];
          const float4 a = q0v[j], c = q1v[j];
          acc[tt][0] = fmaf(k.x, a.x, fmaf(k.y, a.y, fmaf(k.z, a.z, fmaf(k.w, a.w, acc[tt][0]))));
          acc[tt][1] = fmaf(k.x, c.x, fmaf(k.y, c.y, fmaf(k.z, c.z, fmaf(k.w, c.w, acc[tt][1]))));
        }
      }
      // reduce over the 16 c-split lanes (DPP, VALU pipe)
#pragma unroll
      for (int tt = 0; tt < 8; ++tt) {
        acc[tt][0] = rsum16(acc[tt][0]);
        acc[tt][1] = rsum16(acc[tt][1]);
      }
      if (cs == 0) {
#pragma unroll
        for (int tt = 0; tt < 8; ++tt) {
          float2 v; v.x = acc[tt][0] * SCALE_; v.y = acc[tt][1] * SCALE_;
          *(float2*)(p_lds + (tg * 8 + tt) * PSTR_ + 2 * hg) = v;
        }
      }
    }
    __syncthreads();

    // --- online softmax: 16 h x 32 t (all 512 threads) ---
    {
      const int h2 = tid >> 5, tl2 = tid & 31;
      const float sv = p_lds[tl2 * PSTR_ + h2];
      float msub = sv;
#pragma unroll
      for (int d = 16; d; d >>= 1) msub = fmaxf(msub, __shfl_xor(msub, d, 32));
      const float mold = m_st[h2];
      const float mnew = fmaxf(mold, msub);
      const float e = __expf(sv - mnew);
      float lsum = e;
#pragma unroll
      for (int d = 16; d; d >>= 1) lsum += __shfl_xor(lsum, d, 32);
      p_lds[tl2 * PSTR_ + h2] = e;
      if (tl2 == 0) {
        const float fac = __expf(mold - mnew);
        f_st[h2] = fac;
        l_st[h2] = l_st[h2] * fac + lsum;
        m_st[h2] = mnew;
      }
    }
    __syncthreads();

    // --- PV accumulate: o[c-quad][h-quad] over 32 t ---
    {
      const float4 fv = *(const float4*)(f_st + 4 * h4p);
#pragma unroll
      for (int cc = 0; cc < 4; ++cc) {
        o[cc][0] *= fv.x; o[cc][1] *= fv.y; o[cc][2] *= fv.z; o[cc][3] *= fv.w;
      }
#pragma unroll 8
      for (int t = 0; t < TS_; ++t) {
        const float4 kq = *(const float4*)(bufc + t * CE_ + 4 * c4p);
        const float4 pq = *(const float4*)(p_lds + t * PSTR_ + 4 * h4p);
        o[0][0] = fmaf(pq.x, kq.x, o[0][0]); o[0][1] = fmaf(pq.y, kq.x, o[0][1]);
        o[0][2] = fmaf(pq.z, kq.x, o[0][2]); o[0][3] = fmaf(pq.w, kq.x, o[0][3]);
        o[1][0] = fmaf(pq.x, kq.y, o[1][0]); o[1][1] = fmaf(pq.y, kq.y, o[1][1]);
        o[1][2] = fmaf(pq.z, kq.y, o[1][2]); o[1][3] = fmaf(pq.w, kq.y, o[1][3]);
        o[2][0] = fmaf(pq.x, kq.z, o[2][0]); o[2][1] = fmaf(pq.y, kq.z, o[2][1]);
        o[2][2] = fmaf(pq.z, kq.z, o[2][2]); o[2][3] = fmaf(pq.w, kq.z, o[2][3]);
        o[3][0] = fmaf(pq.x, kq.w, o[3][0]); o[3][1] = fmaf(pq.y, kq.w, o[3][1]);
        o[3][2] = fmaf(pq.z, kq.w, o[3][2]); o[3][3] = fmaf(pq.w, kq.w, o[3][3]);
      }
    }
  }

  // --- write chunk partials ---
  {
    float* Op = ws + WS_OPART;
#pragma unroll
    for (int hh = 0; hh < 4; ++hh) {
      const int h = 4 * h4p + hh;
      float4 v;
      v.x = o[0][hh]; v.y = o[1][hh]; v.z = o[2][hh]; v.w = o[3][hh];
      *(float4*)(Op + ((size_t)(b * H_ + h) * NCH_ + chunk) * KVLR_ + 4 * c4p) = v;
    }
    if (tid < H_) {
      ws[WS_MLOC + (b * H_ + tid) * NCH_ + chunk] = m_st[tid];
      ws[WS_LLOC + (b * H_ + tid) * NCH_ + chunk] = l_st[tid];
    }
  }
}

// ---------------- K6: combine partials + project through wkv_b[:,128:,:] ----------------
__global__ __launch_bounds__(256) void mla_k6(const float* __restrict__ wkvb,
                                              float* __restrict__ ws) {
  const int h = blockIdx.x, b = blockIdx.y;
  __shared__ float wgt[NCH_];
  __shared__ float ao[KVLR_];
  __shared__ float Linv;
  const int tid = threadIdx.x;
  if (tid < NCH_) {   // 32 lanes: combine weights
    const float m = ws[WS_MLOC + (b * H_ + h) * NCH_ + tid];
    float M = m;
#pragma unroll
    for (int s = 16; s; s >>= 1) M = fmaxf(M, __shfl_xor(M, s, 32));
    const float wv = __expf(m - M);
    wgt[tid] = wv;
    float lv = ws[WS_LLOC + (b * H_ + h) * NCH_ + tid] * wv;
#pragma unroll
    for (int s = 16; s; s >>= 1) lv += __shfl_xor(lv, s, 32);
    if (tid == 0) Linv = 1.0f / lv;
  }
  __syncthreads();
  const float* Ob = ws + WS_OPART + (size_t)(b * H_ + h) * NCH_ * KVLR_;
  float s0 = 0.f, s1 = 0.f;
#pragma unroll 4
  for (int i = 0; i < NCH_; ++i) {
    const float wv = wgt[i];
    s0 = fmaf(wv, Ob[(size_t)i * KVLR_ + tid], s0);
    s1 = fmaf(wv, Ob[(size_t)i * KVLR_ + tid + 256], s1);
  }
  const float li = Linv;
  ao[tid] = s0 * li;
  ao[tid + 256] = s1 * li;
  __syncthreads();
  const int v = tid >> 1, half = tid & 1;
  const float* w2 = wkvb + ((size_t)h * 256 + DN_ + v) * KVLR_ + half * 256;
  const float* a = ao + half * 256;
  float s = 0.f;
#pragma unroll
  for (int c = 0; c < 256; c += 4) {
    const float4 wv = *(const float4*)(w2 + c);
    s = fmaf(wv.x, a[c], s);
    s = fmaf(wv.y, a[c + 1], s);
    s = fmaf(wv.z, a[c + 2], s);
    s = fmaf(wv.w, a[c + 3], s);
  }
  s += __shfl_xor(s, 1);
  if (half == 0) ws[WS_OUT2 + b * DIM_ + h * DV_ + v] = s;
}

// ---------------- K7: y = out2 @ wo^T + wo_b ----------------
__global__ __launch_bounds__(256) void mla_k7(const float* __restrict__ wo,
                                              const float* __restrict__ wob,
                                              const float* __restrict__ ws,
                                              float* __restrict__ out) {
  const int w = threadIdx.x >> 6, l = threadIdx.x & 63;
  const int r = blockIdx.x * 4 + w;  // 0..2047
  const float4* wp = (const float4*)(wo + (size_t)r * DIM_);
  const float4* x4 = (const float4*)(ws + WS_OUT2);
  float4 wv[8];
#pragma unroll
  for (int j = 0; j < 8; ++j) wv[j] = wp[l + 64 * j];
  float acc[B_];
#pragma unroll
  for (int b = 0; b < B_; ++b) acc[b] = 0.f;
#pragma unroll
  for (int b = 0; b < B_; ++b) {
#pragma unroll
    for (int j = 0; j < 8; ++j) {
      const float4 xv = x4[b * (DIM_ / 4) + l + 64 * j];
      acc[b] = fmaf(wv[j].x, xv.x, fmaf(wv[j].y, xv.y, fmaf(wv[j].z, xv.z, fmaf(wv[j].w, xv.w, acc[b]))));
    }
  }
#pragma unroll
  for (int b = 0; b < B_; ++b)
#pragma unroll
    for (int s = 32; s; s >>= 1) acc[b] += __shfl_xor(acc[b], s);
  if (l == 0) {
    const float b0 = wob[r];
#pragma unroll
    for (int b = 0; b < B_; ++b) out[b * DIM_ + r] = acc[b] + b0;
  }
}

extern "C" void kernel_launch(void* const* d_in, const int* in_sizes, int n_in,
                              void* d_out, int out_size, void* d_ws, size_t ws_size,
                              hipStream_t stream) {
  (void)in_sizes; (void)n_in; (void)out_size; (void)ws_size;
  const float* x     = (const float*)d_in[0];
  const float* fcos  = (const float*)d_in[2];
  const float* fsin  = (const float*)d_in[3];
  const float* kvpre = (const float*)d_in[4];
  const float* pepre = (const float*)d_in[5];
  const float* wqa   = (const float*)d_in[6];
  const float* bqa   = (const float*)d_in[7];
  const float* qnw   = (const float*)d_in[8];
  const float* wqb   = (const float*)d_in[9];
  const float* bqb   = (const float*)d_in[10];
  const float* wkva  = (const float*)d_in[11];
  const float* bkva  = (const float*)d_in[12];
  const float* kvnw  = (const float*)d_in[13];
  const float* wkvb  = (const float*)d_in[14];
  const float* wo    = (const float*)d_in[15];
  const float* wob   = (const float*)d_in[16];
  float* ws  = (float*)d_ws;
  float* out = (float*)d_out;

  mla_k1<<<dim3((QLR_ + CE_) / 4), dim3(256), 0, stream>>>(x, wqa, bqa, wkva, bkva, ws);
  mla_k2<<<dim3(1), dim3(256), 0, stream>>>(kvnw, fcos, fsin, ws);
  mla_k3<<<dim3(H_ * (DN_ + DR_) / 8), dim3(256), 0, stream>>>(qnw, wqb, bqb, fcos, fsin, ws);
  mla_k4<<<dim3(16, H_), dim3(256), 0, stream>>>(wkvb, ws);
  mla_k5<<<dim3(NCH_, B_), dim3(512), 0, stream>>>(kvpre, pepre, ws);
  mla_k6<<<dim3(H_, B_), dim3(256), 0, stream>>>(wkvb, ws);
  mla_k7<<<dim3(DIM_ / 4), dim3(256), 0, stream>>>(wo, wob, ws, out);
}

// Round 5
// 346.887 us; speedup vs baseline: 1.2156x; 1.2156x over previous
//
#include <hip/hip_runtime.h>
#include <math.h>

namespace {
constexpr int B_   = 8;
constexpr int DIM_ = 2048;
constexpr int H_   = 16;
constexpr int QLR_ = 1536;
constexpr int KVLR_= 512;
constexpr int DN_  = 128;
constexpr int DR_  = 64;
constexpr int DV_  = 128;
constexpr int TPRE_= 8191;
constexpr int CE_  = 576;    // KVLR + DR
constexpr int NCH_ = 32;     // chunks over T=8192
constexpr int CT_  = 256;    // t per chunk
constexpr int TS_  = 32;     // rows per LDS subtile (double-buffered)
constexpr int PSTR_= 20;     // p_lds row stride
constexpr float EPS_ = 1e-6f;
constexpr float SCALE_ = 0.07216878364870322f; // (DN+DR)^-0.5

// workspace layout (float offsets)
constexpr size_t WS_QLAT  = 0;
constexpr size_t WS_KVPE  = WS_QLAT  + (size_t)B_*QLR_;
constexpr size_t WS_KVNEW = WS_KVPE  + (size_t)B_*CE_;
constexpr size_t WS_PENEW = WS_KVNEW + (size_t)B_*KVLR_;
constexpr size_t WS_QRS   = WS_PENEW + (size_t)B_*DR_;
constexpr size_t WS_QNOPE = WS_QRS   + (size_t)B_;
constexpr size_t WS_QT    = WS_QNOPE + (size_t)B_*H_*DN_;   // qTT: [b][h][576]
constexpr size_t WS_MLOC  = WS_QT    + (size_t)B_*CE_*H_;
constexpr size_t WS_LLOC  = WS_MLOC  + (size_t)B_*H_*NCH_;
constexpr size_t WS_OUT2  = WS_LLOC  + (size_t)B_*H_*NCH_;
constexpr size_t WS_OPART = WS_OUT2  + (size_t)B_*DIM_;     // [b][h][chunk][512]
} // namespace

__device__ __forceinline__ void gload16(const float* src, float* ldsDst) {
  __builtin_amdgcn_global_load_lds((const __attribute__((address_space(1))) void*)src,
                                   (__attribute__((address_space(3))) void*)ldsDst,
                                   16, 0, 0);
}

// sum across each 16-lane group via DPP (VALU pipe, keeps DS unit free)
__device__ __forceinline__ float rsum16(float v) {
  int x = __float_as_int(v);
  v += __int_as_float(__builtin_amdgcn_update_dpp(0, x, 0xB1, 0xF, 0xF, true));  // quad_perm xor1
  x = __float_as_int(v);
  v += __int_as_float(__builtin_amdgcn_update_dpp(0, x, 0x4E, 0xF, 0xF, true));  // quad_perm xor2
  x = __float_as_int(v);
  v += __int_as_float(__builtin_amdgcn_update_dpp(0, x, 0x141, 0xF, 0xF, true)); // row_half_mirror
  x = __float_as_int(v);
  v += __int_as_float(__builtin_amdgcn_update_dpp(0, x, 0x140, 0xF, 0xF, true)); // row_mirror
  return v;
}

// ---------------- K1: q_latent = x@wq_a^T + b ; kvpe = x@wkv_a^T + b ----------------
__global__ __launch_bounds__(256) void mla_k1(const float* __restrict__ x,
                                              const float* __restrict__ wqa,
                                              const float* __restrict__ bqa,
                                              const float* __restrict__ wkva,
                                              const float* __restrict__ bkva,
                                              float* __restrict__ ws) {
  const int w = threadIdx.x >> 6, l = threadIdx.x & 63;
  const int r = blockIdx.x * 4 + w;  // 0..2111
  const float* W; const float* bias; float* out; int rr; int ostride;
  if (r < QLR_) { W = wqa;  bias = bqa;  out = ws + WS_QLAT; rr = r;        ostride = QLR_; }
  else          { W = wkva; bias = bkva; out = ws + WS_KVPE; rr = r - QLR_; ostride = CE_;  }
  const float4* wp = (const float4*)(W + (size_t)rr * DIM_);
  const float4* x4 = (const float4*)x;
  float4 wv[8];
#pragma unroll
  for (int j = 0; j < 8; ++j) wv[j] = wp[l + 64 * j];
  float acc[B_];
#pragma unroll
  for (int b = 0; b < B_; ++b) acc[b] = 0.f;
#pragma unroll
  for (int b = 0; b < B_; ++b) {
#pragma unroll
    for (int j = 0; j < 8; ++j) {
      const float4 xv = x4[b * (DIM_ / 4) + l + 64 * j];
      acc[b] = fmaf(wv[j].x, xv.x, fmaf(wv[j].y, xv.y, fmaf(wv[j].z, xv.z, fmaf(wv[j].w, xv.w, acc[b]))));
    }
  }
#pragma unroll
  for (int b = 0; b < B_; ++b)
#pragma unroll
    for (int s = 32; s; s >>= 1) acc[b] += __shfl_xor(acc[b], s);
  if (l == 0) {
    const float b0 = bias[rr];
#pragma unroll
    for (int b = 0; b < B_; ++b) out[b * ostride + rr] = acc[b] + b0;
  }
}

// ---------------- K2: kv rms-norm + k_pe rope + q rms scales ----------------
__global__ __launch_bounds__(256) void mla_k2(const float* __restrict__ kvnw,
                                              const float* __restrict__ fcos,
                                              const float* __restrict__ fsin,
                                              float* __restrict__ ws) {
  const int tid = threadIdx.x;
  const int b = tid >> 5, i = tid & 31;
  const float* kvpe = ws + WS_KVPE + b * CE_;
  float ss = 0.f;
#pragma unroll
  for (int j = 0; j < KVLR_ / 32; ++j) { const float v = kvpe[i + 32 * j]; ss = fmaf(v, v, ss); }
#pragma unroll
  for (int s = 16; s; s >>= 1) ss += __shfl_xor(ss, s, 32);
  const float scale = 1.0f / sqrtf(ss / (float)KVLR_ + EPS_);
  float* kvn = ws + WS_KVNEW + b * KVLR_;
#pragma unroll
  for (int j = 0; j < KVLR_ / 32; ++j) {
    const int c = i + 32 * j;
    kvn[c] = kvpe[c] * kvnw[c] * scale;
  }
  { // rope new k_pe
    const float xr = kvpe[KVLR_ + 2 * i], xi = kvpe[KVLR_ + 2 * i + 1];
    const float c = fcos[i], s = fsin[i];
    float* pen = ws + WS_PENEW + b * DR_;
    pen[2 * i]     = xr * c - xi * s;
    pen[2 * i + 1] = xr * s + xi * c;
  }
  { // q latent rms scale per batch
    const float* p = ws + WS_QLAT + b * QLR_;
    float sq = 0.f;
#pragma unroll
    for (int j = 0; j < QLR_ / 32; ++j) { const float v = p[i + 32 * j]; sq = fmaf(v, v, sq); }
#pragma unroll
    for (int s = 16; s; s >>= 1) sq += __shfl_xor(sq, s, 32);
    if (i == 0) ws[WS_QRS + b] = 1.0f / sqrtf(sq / (float)QLR_ + EPS_);
  }
}

// ---------------- K3: q = rms(q_lat)*g @ wq_b^T + b ; split nope / rope(pe) ----------------
__global__ __launch_bounds__(256) void mla_k3(const float* __restrict__ qnw,
                                              const float* __restrict__ wqb,
                                              const float* __restrict__ bqb,
                                              const float* __restrict__ fcos,
                                              const float* __restrict__ fsin,
                                              float* __restrict__ ws) {
  const int w = threadIdx.x >> 6, l = threadIdx.x & 63;
  const int r0 = blockIdx.x * 8 + w * 2;  // 0..3070
  const float4* w0p = (const float4*)(wqb + (size_t)r0 * QLR_);
  const float4* w1p = (const float4*)(wqb + (size_t)(r0 + 1) * QLR_);
  const float4* g4  = (const float4*)qnw;
  const float4* x4  = (const float4*)(ws + WS_QLAT);
  float4 wg0[6], wg1[6];
#pragma unroll
  for (int j = 0; j < 6; ++j) {
    const int c4 = l + 64 * j;
    const float4 a = w0p[c4], bb = w1p[c4], g = g4[c4];
    wg0[j].x = a.x * g.x; wg0[j].y = a.y * g.y; wg0[j].z = a.z * g.z; wg0[j].w = a.w * g.w;
    wg1[j].x = bb.x * g.x; wg1[j].y = bb.y * g.y; wg1[j].z = bb.z * g.z; wg1[j].w = bb.w * g.w;
  }
  float acc0[B_], acc1[B_];
#pragma unroll
  for (int b = 0; b < B_; ++b) { acc0[b] = 0.f; acc1[b] = 0.f; }
#pragma unroll
  for (int b = 0; b < B_; ++b) {
#pragma unroll
    for (int j = 0; j < 6; ++j) {
      const float4 xv = x4[b * (QLR_ / 4) + l + 64 * j];
      acc0[b] = fmaf(wg0[j].x, xv.x, fmaf(wg0[j].y, xv.y, fmaf(wg0[j].z, xv.z, fmaf(wg0[j].w, xv.w, acc0[b]))));
      acc1[b] = fmaf(wg1[j].x, xv.x, fmaf(wg1[j].y, xv.y, fmaf(wg1[j].z, xv.z, fmaf(wg1[j].w, xv.w, acc1[b]))));
    }
  }
#pragma unroll
  for (int b = 0; b < B_; ++b)
#pragma unroll
    for (int s = 32; s; s >>= 1) {
      acc0[b] += __shfl_xor(acc0[b], s);
      acc1[b] += __shfl_xor(acc1[b], s);
    }
  if (l == 0) {
    const int h = r0 / (DN_ + DR_);
    const int j0 = r0 - h * (DN_ + DR_);
    const float b0 = bqb[r0], b1 = bqb[r0 + 1];
    if (j0 < DN_) {
      float* qn = ws + WS_QNOPE;
#pragma unroll
      for (int b = 0; b < B_; ++b) {
        const float sb = ws[WS_QRS + b];
        qn[(b * H_ + h) * DN_ + j0]     = acc0[b] * sb + b0;
        qn[(b * H_ + h) * DN_ + j0 + 1] = acc1[b] * sb + b1;
      }
    } else {
      const int i = (j0 - DN_) >> 1;
      const float c = fcos[i], s = fsin[i];
      float* qTT = ws + WS_QT;
#pragma unroll
      for (int b = 0; b < B_; ++b) {
        const float sb = ws[WS_QRS + b];
        const float xr = acc0[b] * sb + b0, xi = acc1[b] * sb + b1;
        qTT[((size_t)(b * H_ + h)) * CE_ + KVLR_ + 2 * i]     = xr * c - xi * s;
        qTT[((size_t)(b * H_ + h)) * CE_ + KVLR_ + 2 * i + 1] = xr * s + xi * c;
      }
    }
  }
}

// ---------------- K4: q_abs[b][h][c] = sum_d q_nope[b][h][d] * wkv_b[h][d][c] ----------------
__global__ __launch_bounds__(256) void mla_k4(const float* __restrict__ wkvb,
                                              float* __restrict__ ws) {
  __shared__ float red[7 * 32 * B_];
  const int h = blockIdx.y;
  const int strip = blockIdx.x;
  const int tid = threadIdx.x;
  const int c = tid & 31, dg = tid >> 5;
  const int cg = strip * 32 + c;
  const float* qn = ws + WS_QNOPE;
  float acc[B_];
#pragma unroll
  for (int b = 0; b < B_; ++b) acc[b] = 0.f;
  const float* wp = wkvb + (size_t)h * 256 * KVLR_ + cg;
#pragma unroll
  for (int dd = 0; dd < 16; ++dd) {
    const int d = dg * 16 + dd;
    const float wv = wp[(size_t)d * KVLR_];
#pragma unroll
    for (int b = 0; b < B_; ++b) acc[b] = fmaf(qn[(b * H_ + h) * DN_ + d], wv, acc[b]);
  }
  if (dg > 0) {
#pragma unroll
    for (int b = 0; b < B_; ++b) red[(((dg - 1) * 32) + c) * B_ + b] = acc[b];
  }
  __syncthreads();
  if (dg == 0) {
    float* qTT = ws + WS_QT;
#pragma unroll
    for (int b = 0; b < B_; ++b) {
      float v = acc[b];
#pragma unroll
      for (int g = 0; g < 7; ++g) v += red[(g * 32 + c) * B_ + b];
      qTT[((size_t)(b * H_ + h)) * CE_ + cg] = v;
    }
  }
}

// ---------------- K5: fused flash-decode, q-in-registers, spill-free ----------------
// 512 thr, grid (32, 8), 1 block/CU (147 KB LDS). TS=32 double-buffered kv via
// global_load_lds. Score: thread = (t8-group, h-pair, c-split16); q[2][36]
// persistent in VGPRs; tt-outer loop keeps live state ~110 VGPRs (no kv[] buffer
// -> no spill, R4's regression). DPP reduce over 16 c-split lanes. PV: thread =
// (c-quad, h-quad), o[4][4] persistent. All 8 waves active in every phase.
__global__ __launch_bounds__(512) void mla_k5(const float* __restrict__ kvpre,
                                              const float* __restrict__ pepre,
                                              float* __restrict__ ws) {
  __shared__ float kv_lds[2][TS_ * CE_];  // 2 x 32 x 576 x 4B = 147.5 KB
  __shared__ float p_lds[TS_ * PSTR_];    // 2.5 KB
  __shared__ float m_st[H_], l_st[H_], f_st[H_];

  const int b = blockIdx.y, chunk = blockIdx.x;
  const int t0 = chunk * CT_;
  const int tid = threadIdx.x;
  const int w = tid >> 6, l = tid & 63;
  // score roles
  const int cs = l & 15;             // c-split: 36 floats each
  const int hl = l >> 4;             // 0..3
  const int tg = w >> 1;             // t-group: rows tg*8 .. tg*8+7
  const int hg = (w & 1) * 4 + hl;   // 0..7 -> heads 2hg, 2hg+1
  // PV roles
  const int c4p = tid >> 2, h4p = tid & 3;

  const float* kvnew = ws + WS_KVNEW + b * KVLR_;
  const float* penew = ws + WS_PENEW + b * DR_;

  auto stageKV = [&](float* buf, int s) {
    const int ts0 = t0 + s * TS_;
#pragma unroll
    for (int k = 0; k < 9; ++k) {          // 32*576/4 = 4608 f4 / 512 thr = 9
      const int i = w + 8 * k;             // wave-strided instr index
      const int f = i * 64 + l;            // f4 index in subtile
      const int tl = f / 144;
      const int c4 = f - tl * 144;
      const int tgl = ts0 + tl;
      const float* src;
      if (tgl < TPRE_) {
        src = (c4 < 128) ? (kvpre + ((size_t)b * TPRE_ + tgl) * KVLR_ + 4 * c4)
                         : (pepre + ((size_t)b * TPRE_ + tgl) * DR_ + 4 * (c4 - 128));
      } else {
        src = (c4 < 128) ? (kvnew + 4 * c4) : (penew + 4 * (c4 - 128));
      }
      gload16(src, buf + (size_t)i * 64 * 4);
    }
  };

  stageKV(kv_lds[0], 0);   // start HBM early

  // --- persistent q registers: heads 2hg, 2hg+1, c-range [cs*36, cs*36+36) ---
  float4 q0v[9], q1v[9];
  {
    const float* qb0 = ws + WS_QT + ((size_t)(b * H_) + 2 * hg) * CE_ + cs * 36;
    const float* qb1 = qb0 + CE_;
#pragma unroll
    for (int j = 0; j < 9; ++j) {
      q0v[j] = *(const float4*)(qb0 + 4 * j);
      q1v[j] = *(const float4*)(qb1 + 4 * j);
    }
  }
  if (tid < H_) { m_st[tid] = -3.4e38f; l_st[tid] = 0.f; }

  float o[4][4];
#pragma unroll
  for (int cc = 0; cc < 4; ++cc)
#pragma unroll
    for (int hh = 0; hh < 4; ++hh) o[cc][hh] = 0.f;

  for (int s = 0; s < CT_ / TS_; ++s) {   // 8 subtiles of 32 rows
    __syncthreads();                       // buf[s&1] staged; prev PV reads done
    if (s + 1 < CT_ / TS_) stageKV(kv_lds[(s + 1) & 1], s + 1);  // prefetch
    const float* bufc = kv_lds[s & 1];

    // --- scores: 8 t-rows x 2 h x 36 c per thread; tt-outer keeps regs low ---
    {
      const float* kb = bufc + (tg * 8) * CE_ + cs * 36;
#pragma unroll
      for (int tt = 0; tt < 8; ++tt) {
        const float* kr = kb + tt * CE_;
        float a0 = 0.f, a1 = 0.f;
#pragma unroll
        for (int j = 0; j < 9; ++j) {
          const float4 k = *(const float4*)(kr + 4 * j);
          const float4 qa = q0v[j], qc = q1v[j];
          a0 = fmaf(k.x, qa.x, fmaf(k.y, qa.y, fmaf(k.z, qa.z, fmaf(k.w, qa.w, a0))));
          a1 = fmaf(k.x, qc.x, fmaf(k.y, qc.y, fmaf(k.z, qc.z, fmaf(k.w, qc.w, a1))));
        }
        a0 = rsum16(a0);
        a1 = rsum16(a1);
        if (cs == 0) {
          float2 v; v.x = a0 * SCALE_; v.y = a1 * SCALE_;
          *(float2*)(p_lds + (tg * 8 + tt) * PSTR_ + 2 * hg) = v;
        }
      }
    }
    __syncthreads();

    // --- online softmax: 16 h x 32 t (all 512 threads) ---
    {
      const int h2 = tid >> 5, tl2 = tid & 31;
      const float sv = p_lds[tl2 * PSTR_ + h2];
      float msub = sv;
#pragma unroll
      for (int d = 16; d; d >>= 1) msub = fmaxf(msub, __shfl_xor(msub, d, 32));
      const float mold = m_st[h2];
      const float mnew = fmaxf(mold, msub);
      const float e = __expf(sv - mnew);
      float lsum = e;
#pragma unroll
      for (int d = 16; d; d >>= 1) lsum += __shfl_xor(lsum, d, 32);
      p_lds[tl2 * PSTR_ + h2] = e;
      if (tl2 == 0) {
        const float fac = __expf(mold - mnew);
        f_st[h2] = fac;
        l_st[h2] = l_st[h2] * fac + lsum;
        m_st[h2] = mnew;
      }
    }
    __syncthreads();

    // --- PV accumulate: o[c-quad][h-quad] over 32 t ---
    {
      const float4 fv = *(const float4*)(f_st + 4 * h4p);
#pragma unroll
      for (int cc = 0; cc < 4; ++cc) {
        o[cc][0] *= fv.x; o[cc][1] *= fv.y; o[cc][2] *= fv.z; o[cc][3] *= fv.w;
      }
#pragma unroll 8
      for (int t = 0; t < TS_; ++t) {
        const float4 kq = *(const float4*)(bufc + t * CE_ + 4 * c4p);
        const float4 pq = *(const float4*)(p_lds + t * PSTR_ + 4 * h4p);
        o[0][0] = fmaf(pq.x, kq.x, o[0][0]); o[0][1] = fmaf(pq.y, kq.x, o[0][1]);
        o[0][2] = fmaf(pq.z, kq.x, o[0][2]); o[0][3] = fmaf(pq.w, kq.x, o[0][3]);
        o[1][0] = fmaf(pq.x, kq.y, o[1][0]); o[1][1] = fmaf(pq.y, kq.y, o[1][1]);
        o[1][2] = fmaf(pq.z, kq.y, o[1][2]); o[1][3] = fmaf(pq.w, kq.y, o[1][3]);
        o[2][0] = fmaf(pq.x, kq.z, o[2][0]); o[2][1] = fmaf(pq.y, kq.z, o[2][1]);
        o[2][2] = fmaf(pq.z, kq.z, o[2][2]); o[2][3] = fmaf(pq.w, kq.z, o[2][3]);
        o[3][0] = fmaf(pq.x, kq.w, o[3][0]); o[3][1] = fmaf(pq.y, kq.w, o[3][1]);
        o[3][2] = fmaf(pq.z, kq.w, o[3][2]); o[3][3] = fmaf(pq.w, kq.w, o[3][3]);
      }
    }
  }

  // --- write chunk partials ---
  {
    float* Op = ws + WS_OPART;
#pragma unroll
    for (int hh = 0; hh < 4; ++hh) {
      const int h = 4 * h4p + hh;
      float4 v;
      v.x = o[0][hh]; v.y = o[1][hh]; v.z = o[2][hh]; v.w = o[3][hh];
      *(float4*)(Op + ((size_t)(b * H_ + h) * NCH_ + chunk) * KVLR_ + 4 * c4p) = v;
    }
    if (tid < H_) {
      ws[WS_MLOC + (b * H_ + tid) * NCH_ + chunk] = m_st[tid];
      ws[WS_LLOC + (b * H_ + tid) * NCH_ + chunk] = l_st[tid];
    }
  }
}

// ---------------- K6: combine partials + project through wkv_b[:,128:,:] ----------------
__global__ __launch_bounds__(256) void mla_k6(const float* __restrict__ wkvb,
                                              float* __restrict__ ws) {
  const int h = blockIdx.x, b = blockIdx.y;
  __shared__ float wgt[NCH_];
  __shared__ float ao[KVLR_];
  __shared__ float Linv;
  const int tid = threadIdx.x;
  if (tid < NCH_) {   // 32 lanes: combine weights
    const float m = ws[WS_MLOC + (b * H_ + h) * NCH_ + tid];
    float M = m;
#pragma unroll
    for (int s = 16; s; s >>= 1) M = fmaxf(M, __shfl_xor(M, s, 32));
    const float wv = __expf(m - M);
    wgt[tid] = wv;
    float lv = ws[WS_LLOC + (b * H_ + h) * NCH_ + tid] * wv;
#pragma unroll
    for (int s = 16; s; s >>= 1) lv += __shfl_xor(lv, s, 32);
    if (tid == 0) Linv = 1.0f / lv;
  }
  __syncthreads();
  const float* Ob = ws + WS_OPART + (size_t)(b * H_ + h) * NCH_ * KVLR_;
  float s0 = 0.f, s1 = 0.f;
#pragma unroll 4
  for (int i = 0; i < NCH_; ++i) {
    const float wv = wgt[i];
    s0 = fmaf(wv, Ob[(size_t)i * KVLR_ + tid], s0);
    s1 = fmaf(wv, Ob[(size_t)i * KVLR_ + tid + 256], s1);
  }
  const float li = Linv;
  ao[tid] = s0 * li;
  ao[tid + 256] = s1 * li;
  __syncthreads();
  const int v = tid >> 1, half = tid & 1;
  const float* w2 = wkvb + ((size_t)h * 256 + DN_ + v) * KVLR_ + half * 256;
  const float* a = ao + half * 256;
  float s = 0.f;
#pragma unroll
  for (int c = 0; c < 256; c += 4) {
    const float4 wv = *(const float4*)(w2 + c);
    s = fmaf(wv.x, a[c], s);
    s = fmaf(wv.y, a[c + 1], s);
    s = fmaf(wv.z, a[c + 2], s);
    s = fmaf(wv.w, a[c + 3], s);
  }
  s += __shfl_xor(s, 1);
  if (half == 0) ws[WS_OUT2 + b * DIM_ + h * DV_ + v] = s;
}

// ---------------- K7: y = out2 @ wo^T + wo_b ----------------
__global__ __launch_bounds__(256) void mla_k7(const float* __restrict__ wo,
                                              const float* __restrict__ wob,
                                              const float* __restrict__ ws,
                                              float* __restrict__ out) {
  const int w = threadIdx.x >> 6, l = threadIdx.x & 63;
  const int r = blockIdx.x * 4 + w;  // 0..2047
  const float4* wp = (const float4*)(wo + (size_t)r * DIM_);
  const float4* x4 = (const float4*)(ws + WS_OUT2);
  float4 wv[8];
#pragma unroll
  for (int j = 0; j < 8; ++j) wv[j] = wp[l + 64 * j];
  float acc[B_];
#pragma unroll
  for (int b = 0; b < B_; ++b) acc[b] = 0.f;
#pragma unroll
  for (int b = 0; b < B_; ++b) {
#pragma unroll
    for (int j = 0; j < 8; ++j) {
      const float4 xv = x4[b * (DIM_ / 4) + l + 64 * j];
      acc[b] = fmaf(wv[j].x, xv.x, fmaf(wv[j].y, xv.y, fmaf(wv[j].z, xv.z, fmaf(wv[j].w, xv.w, acc[b]))));
    }
  }
#pragma unroll
  for (int b = 0; b < B_; ++b)
#pragma unroll
    for (int s = 32; s; s >>= 1) acc[b] += __shfl_xor(acc[b], s);
  if (l == 0) {
    const float b0 = wob[r];
#pragma unroll
    for (int b = 0; b < B_; ++b) out[b * DIM_ + r] = acc[b] + b0;
  }
}

extern "C" void kernel_launch(void* const* d_in, const int* in_sizes, int n_in,
                              void* d_out, int out_size, void* d_ws, size_t ws_size,
                              hipStream_t stream) {
  (void)in_sizes; (void)n_in; (void)out_size; (void)ws_size;
  const float* x     = (const float*)d_in[0];
  const float* fcos  = (const float*)d_in[2];
  const float* fsin  = (const float*)d_in[3];
  const float* kvpre = (const float*)d_in[4];
  const float* pepre = (const float*)d_in[5];
  const float* wqa   = (const float*)d_in[6];
  const float* bqa   = (const float*)d_in[7];
  const float* qnw   = (const float*)d_in[8];
  const float* wqb   = (const float*)d_in[9];
  const float* bqb   = (const float*)d_in[10];
  const float* wkva  = (const float*)d_in[11];
  const float* bkva  = (const float*)d_in[12];
  const float* kvnw  = (const float*)d_in[13];
  const float* wkvb  = (const float*)d_in[14];
  const float* wo    = (const float*)d_in[15];
  const float* wob   = (const float*)d_in[16];
  float* ws  = (float*)d_ws;
  float* out = (float*)d_out;

  mla_k1<<<dim3((QLR_ + CE_) / 4), dim3(256), 0, stream>>>(x, wqa, bqa, wkva, bkva, ws);
  mla_k2<<<dim3(1), dim3(256), 0, stream>>>(kvnw, fcos, fsin, ws);
  mla_k3<<<dim3(H_ * (DN_ + DR_) / 8), dim3(256), 0, stream>>>(qnw, wqb, bqb, fcos, fsin, ws);
  mla_k4<<<dim3(16, H_), dim3(256), 0, stream>>>(wkvb, ws);
  mla_k5<<<dim3(NCH_, B_), dim3(512), 0, stream>>>(kvpre, pepre, ws);
  mla_k6<<<dim3(H_, B_), dim3(256), 0, stream>>>(wkvb, ws);
  mla_k7<<<dim3(DIM_ / 4), dim3(256), 0, stream>>>(wo, wob, ws, out);
}